// Round 2
// baseline (2453.414 us; speedup 1.0000x reference)
//
#include <hip/hip_runtime.h>
#include <math.h>

#define B_DIM 16
#define S_LEN 4096
#define C_DIM 512
#define TMAXI 512

// ---------------------------------------------------------------- utilities
__device__ __forceinline__ float wave_reduce_add(float v) {
#pragma unroll
  for (int off = 32; off > 0; off >>= 1) v += __shfl_xor(v, off, 64);
  return v;
}

// ---------------------------------------------------------------- kernel 1: W[co][ci][k] -> Wt[k][ci][co]
__global__ __launch_bounds__(256) void k_transw(const float* __restrict__ w, float* __restrict__ wt) {
  int idx = blockIdx.x * 256 + threadIdx.x;  // over 512*512*3
  if (idx >= C_DIM * C_DIM * 3) return;
  int dk = idx % 3;
  int ci = (idx / 3) % C_DIM;
  int co = idx / (3 * C_DIM);
  wt[((size_t)(dk * C_DIM + ci)) * C_DIM + co] = w[idx];
}

// ---------------------------------------------------------------- kernel 2: conv as f32 GEMM
// C[m=(b,s)][n=c_out] = sum_{dk,ci} x[b, s+dk-1, ci] * Wt[dk*512+ci][n]  (+bias)
#define BM 64
#define BN 64
#define BK 32
__global__ __launch_bounds__(256) void k_conv(const float* __restrict__ x,
                                              const float* __restrict__ wt,
                                              const float* __restrict__ conv_b,
                                              float* __restrict__ h) {
  __shared__ float As[BK][BM + 4];  // +4 pad: 16B-aligned rows, reduced write conflicts
  __shared__ float Bs[BK][BN];
  const int n0 = blockIdx.x * BN;   // fast-varying: 8 n-blocks share same A tile (L2 reuse of x)
  const int m0 = blockIdx.y * BM;
  const int b = m0 >> 12;
  const int s0 = m0 & (S_LEN - 1);
  const int t = threadIdx.x;
  const int tx = t & 15, ty = t >> 4;
  const float* xb = x + (size_t)b * S_LEN * C_DIM;

  float acc[4][4];
#pragma unroll
  for (int i = 0; i < 4; ++i)
#pragma unroll
    for (int j = 0; j < 4; ++j) acc[i][j] = 0.f;

  for (int q = 0; q < 48; ++q) {  // K = 3*512 in chunks of 32
    const int dk = q >> 4;
    const int ci0 = (q & 15) << 5;
    // stage A (im2col with SAME padding), store transposed [kk][m]
#pragma unroll
    for (int r = 0; r < 8; ++r) {
      int idx = r * 256 + t;
      int mi = idx >> 5;        // 0..63
      int kk = idx & 31;        // 0..31 (=ci offset)
      int s = s0 + mi + dk - 1;
      float v = 0.f;
      if (s >= 0 && s < S_LEN) v = xb[(size_t)s * C_DIM + ci0 + kk];
      As[kk][mi] = v;
    }
    // stage B
    const float* wrow = wt + ((size_t)(dk * C_DIM + ci0)) * C_DIM + n0;
#pragma unroll
    for (int r = 0; r < 8; ++r) {
      int idx = r * 256 + t;
      int kk = idx >> 6;        // 0..31
      int n = idx & 63;
      Bs[kk][n] = wrow[(size_t)kk * C_DIM + n];
    }
    __syncthreads();
#pragma unroll
    for (int kk = 0; kk < BK; ++kk) {
      float4 a4 = *(const float4*)&As[kk][ty * 4];
      float4 b4 = *(const float4*)&Bs[kk][tx * 4];
      float a[4] = {a4.x, a4.y, a4.z, a4.w};
      float bb[4] = {b4.x, b4.y, b4.z, b4.w};
#pragma unroll
      for (int i = 0; i < 4; ++i)
#pragma unroll
        for (int j = 0; j < 4; ++j) acc[i][j] = fmaf(a[i], bb[j], acc[i][j]);
    }
    __syncthreads();
  }
  // epilogue: add bias, store
  float4 bias = *(const float4*)&conv_b[n0 + tx * 4];
#pragma unroll
  for (int i = 0; i < 4; ++i) {
    float4 o;
    o.x = acc[i][0] + bias.x;
    o.y = acc[i][1] + bias.y;
    o.z = acc[i][2] + bias.z;
    o.w = acc[i][3] + bias.w;
    *(float4*)&h[((size_t)(m0 + ty * 4 + i)) * C_DIM + n0 + tx * 4] = o;
  }
}

// ---------------------------------------------------------------- kernel 3: LN + GELU(exact) + proj + sigmoid
// one wave per position; 4 positions per 256-thread block
__global__ __launch_bounds__(256) void k_ln(const float* __restrict__ h,
                                            const float* __restrict__ ln_g,
                                            const float* __restrict__ ln_b,
                                            const float* __restrict__ pw,
                                            const float* __restrict__ pb,
                                            const unsigned char* __restrict__ mask,
                                            float* __restrict__ alpha) {
  const int wave = threadIdx.x >> 6;
  const int lane = threadIdx.x & 63;
  const size_t pos = (size_t)blockIdx.x * 4 + wave;  // 0..65535
  const float* hp = h + pos * C_DIM;
  const int c0 = lane * 8;
  float4 v0 = *(const float4*)&hp[c0];
  float4 v1 = *(const float4*)&hp[c0 + 4];
  float v[8] = {v0.x, v0.y, v0.z, v0.w, v1.x, v1.y, v1.z, v1.w};

  float s = 0.f;
#pragma unroll
  for (int j = 0; j < 8; ++j) s += v[j];
  s = wave_reduce_add(s);
  const float mu = s * (1.f / C_DIM);

  float vs = 0.f;
#pragma unroll
  for (int j = 0; j < 8; ++j) {
    float d = v[j] - mu;
    vs += d * d;
  }
  vs = wave_reduce_add(vs);
  const float rs = 1.0f / sqrtf(vs * (1.f / C_DIM) + 1e-5f);

  float4 g0 = *(const float4*)&ln_g[c0];
  float4 g1 = *(const float4*)&ln_g[c0 + 4];
  float4 b0 = *(const float4*)&ln_b[c0];
  float4 b1 = *(const float4*)&ln_b[c0 + 4];
  float4 w0 = *(const float4*)&pw[c0];
  float4 w1 = *(const float4*)&pw[c0 + 4];
  float g[8] = {g0.x, g0.y, g0.z, g0.w, g1.x, g1.y, g1.z, g1.w};
  float bb[8] = {b0.x, b0.y, b0.z, b0.w, b1.x, b1.y, b1.z, b1.w};
  float w[8] = {w0.x, w0.y, w0.z, w0.w, w1.x, w1.y, w1.z, w1.w};

  float dot = 0.f;
#pragma unroll
  for (int j = 0; j < 8; ++j) {
    float y = (v[j] - mu) * rs * g[j] + bb[j];
    float gel = 0.5f * y * (1.0f + erff(y * 0.70710678118654752440f));
    dot += gel * w[j];
  }
  dot = wave_reduce_add(dot);

  if (lane == 0) {
    float z = dot + pb[0];
    float a = 1.f / (1.f + expf(-z));
    if (mask[pos]) a = 0.f;
    alpha[pos] = a;
  }
}

// ---------------------------------------------------------------- kernel 4: per-batch alpha sum
__global__ __launch_bounds__(256) void k_asum(const float* __restrict__ alpha, float* __restrict__ asum) {
  __shared__ float red[256];
  const int b = blockIdx.x;
  const int t = threadIdx.x;
  float s = 0.f;
  for (int i = t; i < S_LEN; i += 256) s += alpha[(size_t)b * S_LEN + i];
  red[t] = s;
  __syncthreads();
  for (int k = 128; k > 0; k >>= 1) {
    if (t < k) red[t] += red[t + k];
    __syncthreads();
  }
  if (t == 0) asum[b] = red[0];
}

// ---------------------------------------------------------------- kernel 5: sequential-order scan (matches np.cumsum)
__global__ __launch_bounds__(256) void k_scan(const float* __restrict__ alpha,
                                              const float* __restrict__ asum,
                                              const int* __restrict__ tlen,
                                              float* __restrict__ alphaS,
                                              float* __restrict__ csum,
                                              int* __restrict__ ridx) {
  __shared__ float buf[B_DIM][257];
  __shared__ float cbuf[B_DIM][257];
  __shared__ int ibuf[B_DIM][257];
  __shared__ float run[B_DIM];
  __shared__ float scl[B_DIM];
  const int t = threadIdx.x;
  if (t < B_DIM) {
    run[t] = 0.f;
    float desired = 1.0f * (float)tlen[t] + 1e-4f;  // BETA*T + CIF_EPS
    scl[t] = desired / asum[t];
  }
  __syncthreads();
  for (int c = 0; c < 16; ++c) {  // 16 chunks of 256 positions
#pragma unroll
    for (int r = 0; r < B_DIM; ++r)
      buf[r][t] = alpha[(size_t)r * S_LEN + c * 256 + t];
    __syncthreads();
    if (t < B_DIM) {
      float r = run[t];
      const float sc = scl[t];
      for (int ss = 0; ss < 256; ++ss) {
        float a = buf[t][ss] * sc;  // element-wise scale (rounded), like ref
        r += a;                     // sequential accumulation, like np.cumsum
        buf[t][ss] = a;
        cbuf[t][ss] = r;
        int ri = (int)floorf(r);
        ibuf[t][ss] = ri > TMAXI ? TMAXI : ri;
      }
      run[t] = r;
    }
    __syncthreads();
#pragma unroll
    for (int r = 0; r < B_DIM; ++r) {
      size_t g = (size_t)r * S_LEN + c * 256 + t;
      alphaS[g] = buf[r][t];
      csum[g] = cbuf[r][t];
      ridx[g] = ibuf[r][t];
    }
    __syncthreads();
  }
}

// ---------------------------------------------------------------- kernel 6: gather output rows
__device__ __forceinline__ int lower_bound(const int* __restrict__ R, int v) {
  int lo = 0, hi = S_LEN;
  while (lo < hi) {
    int m = (lo + hi) >> 1;
    if (R[m] < v) lo = m + 1; else hi = m;
  }
  return lo;
}

__global__ __launch_bounds__(128) void k_out(const float* __restrict__ x,
                                             const float* __restrict__ alphaS,
                                             const float* __restrict__ csum,
                                             const int* __restrict__ ridx,
                                             const int* __restrict__ tlen,
                                             float* __restrict__ out) {
  const int b = blockIdx.y;
  const int tt = blockIdx.x;  // output row 0..511
  const int c4 = threadIdx.x; // 128 threads * float4 = 512 channels
  float4 acc = {0.f, 0.f, 0.f, 0.f};

  if (tt < tlen[b]) {
    const int* R = ridx + (size_t)b * S_LEN;
    const float* aS = alphaS + (size_t)b * S_LEN;
    const float* cS = csum + (size_t)b * S_LEN;
    int lo = lower_bound(R, tt);
    int hi = lower_bound(R, tt + 1);
    if (hi > S_LEN - 1) hi = S_LEN - 1;
    const float* xb = x + ((size_t)b * S_LEN) * C_DIM + c4 * 4;
    for (int s = lo; s <= hi; ++s) {
      int Rs = R[s];
      int Ls = (s > 0) ? R[s - 1] : 0;
      int fire = Rs - Ls;
      float a = aS[s];
      float cs = cS[s];
      float rw = (fire > 0) ? (cs - (float)Rs) : 0.f;  // BETA=1
      int extra = (fire > 1) ? (fire - 1) : 0;
      float lw = a - rw - (float)extra;
      float wgt = 0.f;
      if (Ls == tt) wgt += lw;
      if (fire > 0 && Rs == tt) wgt += rw;
      int t1 = (Ls + 1 < TMAXI) ? (Ls + 1) : TMAXI;
      int t2 = (t1 + 1 < TMAXI) ? (t1 + 1) : TMAXI;
      if (extra >= 1 && t1 == tt) wgt += 1.0f;
      if (extra >= 2 && t2 == tt) wgt += 1.0f;
      if (wgt != 0.f) {
        const float4 xv = *(const float4*)&xb[(size_t)s * C_DIM];
        acc.x = fmaf(wgt, xv.x, acc.x);
        acc.y = fmaf(wgt, xv.y, acc.y);
        acc.z = fmaf(wgt, xv.z, acc.z);
        acc.w = fmaf(wgt, xv.w, acc.w);
      }
    }
  }
  *(float4*)&out[(((size_t)b * TMAXI) + tt) * C_DIM + c4 * 4] = acc;
}

// ---------------------------------------------------------------- launch
extern "C" void kernel_launch(void* const* d_in, const int* in_sizes, int n_in,
                              void* d_out, int out_size, void* d_ws, size_t ws_size,
                              hipStream_t stream) {
  const float* x = (const float*)d_in[0];
  const unsigned char* mask = (const unsigned char*)d_in[1];
  const int* tlen = (const int*)d_in[2];
  const float* conv_w = (const float*)d_in[3];
  const float* conv_b = (const float*)d_in[4];
  const float* ln_g = (const float*)d_in[5];
  const float* ln_b = (const float*)d_in[6];
  const float* proj_w = (const float*)d_in[7];
  const float* proj_b = (const float*)d_in[8];
  float* out = (float*)d_out;

  char* ws = (char*)d_ws;
  const size_t n_pos = (size_t)B_DIM * S_LEN;               // 65536
  float* h = (float*)ws;                                    // 134217728 B
  float* wt = (float*)(ws + (size_t)n_pos * C_DIM * 4);     // 3145728 B
  char* p = ws + (size_t)n_pos * C_DIM * 4 + (size_t)3 * C_DIM * C_DIM * 4;
  float* alpha = (float*)p;            p += n_pos * 4;
  float* alphaS = (float*)p;           p += n_pos * 4;
  float* csumb = (float*)p;            p += n_pos * 4;
  int* ridx = (int*)p;                 p += n_pos * 4;
  float* asum = (float*)p;

  k_transw<<<(C_DIM * C_DIM * 3 + 255) / 256, 256, 0, stream>>>(conv_w, wt);
  k_conv<<<dim3(C_DIM / BN, (B_DIM * S_LEN) / BM), 256, 0, stream>>>(x, wt, conv_b, h);
  k_ln<<<(B_DIM * S_LEN) / 4, 256, 0, stream>>>(h, ln_g, ln_b, proj_w, proj_b, mask, alpha);
  k_asum<<<B_DIM, 256, 0, stream>>>(alpha, asum);
  k_scan<<<1, 256, 0, stream>>>(alpha, asum, tlen, alphaS, csumb, ridx);
  k_out<<<dim3(TMAXI, B_DIM), 128, 0, stream>>>(x, alphaS, csumb, ridx, tlen, out);
}

// Round 3
// 1168.749 us; speedup vs baseline: 2.0992x; 2.0992x over previous
//
#include <hip/hip_runtime.h>
#include <math.h>

#define B_DIM 16
#define S_LEN 4096
#define C_DIM 512
#define TMAXI 512

typedef __attribute__((ext_vector_type(8))) short bfrag;   // 8 bf16 (4 VGPR)
typedef __attribute__((ext_vector_type(4))) float facc;    // 4 f32

__device__ __forceinline__ unsigned short f2bf(float f) {
  unsigned u = __float_as_uint(f);
  unsigned r = u + 0x7FFFu + ((u >> 16) & 1u);
  return (unsigned short)(r >> 16);
}
__device__ __forceinline__ float bf2f(unsigned short h) {
  return __uint_as_float(((unsigned)h) << 16);
}

__device__ __forceinline__ void gload16(const void* g, void* l) {
  __builtin_amdgcn_global_load_lds(
      (const __attribute__((address_space(1))) unsigned int*)g,
      (__attribute__((address_space(3))) unsigned int*)l, 16, 0, 0);
}

__device__ __forceinline__ float wave_reduce_add(float v) {
#pragma unroll
  for (int off = 32; off > 0; off >>= 1) v += __shfl_xor(v, off, 64);
  return v;
}

// ------------------------------------------------ split x -> padded bf16 hi/lo [B][S+2][C]
__global__ __launch_bounds__(256) void k_split_x(const float* __restrict__ x,
                                                 unsigned short* __restrict__ xph,
                                                 unsigned short* __restrict__ xpl) {
  const size_t total = (size_t)B_DIM * (S_LEN + 2) * C_DIM;
  size_t e0 = ((size_t)blockIdx.x * 256 + threadIdx.x) * 8;
  if (e0 >= total) return;
  int b = (int)(e0 / ((size_t)(S_LEN + 2) * C_DIM));
  size_t r = e0 - (size_t)b * (S_LEN + 2) * C_DIM;
  int sp = (int)(r / C_DIM);
  int c = (int)(r % C_DIM);
  unsigned short hv[8], lv[8];
  if (sp == 0 || sp == S_LEN + 1) {
#pragma unroll
    for (int j = 0; j < 8; ++j) { hv[j] = 0; lv[j] = 0; }
  } else {
    const float* xs = &x[((size_t)b * S_LEN + (sp - 1)) * C_DIM + c];
    float4 v0 = *(const float4*)xs;
    float4 v1 = *(const float4*)(xs + 4);
    float vv[8] = {v0.x, v0.y, v0.z, v0.w, v1.x, v1.y, v1.z, v1.w};
#pragma unroll
    for (int j = 0; j < 8; ++j) {
      unsigned short h = f2bf(vv[j]);
      hv[j] = h;
      lv[j] = f2bf(vv[j] - bf2f(h));
    }
  }
  *(uint4*)&xph[e0] = *(const uint4*)hv;
  *(uint4*)&xpl[e0] = *(const uint4*)lv;
}

// ------------------------------------------------ split w[co][ci][dk] -> wsp_{hi,lo}[dk][co][ci]
__global__ __launch_bounds__(256) void k_split_w(const float* __restrict__ w,
                                                 unsigned short* __restrict__ wh,
                                                 unsigned short* __restrict__ wl) {
  int idx = blockIdx.x * 256 + threadIdx.x;  // co*512+ci
  if (idx >= C_DIM * C_DIM) return;
  const float* src = &w[(size_t)idx * 3];
#pragma unroll
  for (int dk = 0; dk < 3; ++dk) {
    float v = src[dk];
    unsigned short h = f2bf(v);
    wh[(size_t)dk * (C_DIM * C_DIM) + idx] = h;
    wl[(size_t)dk * (C_DIM * C_DIM) + idx] = f2bf(v - bf2f(h));
  }
}

// ------------------------------------------------ fused conv(bf16x3 MFMA) + LN + GELU + proj + sigmoid
// block: 512 thr (8 waves, 2x4), tile BM=64 x BN=512, BK=32. LDS rows = 128B (32 hi | 32 lo bf16),
// XOR-swizzled slot^=(row&7); staged via global_load_lds with pre-swizzled global source.
__global__ __launch_bounds__(512) void k_fused(const unsigned short* __restrict__ xph,
                                               const unsigned short* __restrict__ xpl,
                                               const unsigned short* __restrict__ wh,
                                               const unsigned short* __restrict__ wl,
                                               const float* __restrict__ conv_b,
                                               const float* __restrict__ ln_g,
                                               const float* __restrict__ ln_b,
                                               const float* __restrict__ pw,
                                               const float* __restrict__ pb,
                                               const unsigned char* __restrict__ mask,
                                               float* __restrict__ alpha) {
  __shared__ short At[64 * 64];    // 8 KB
  __shared__ short Bt[512 * 64];   // 64 KB

  const int t = threadIdx.x;
  const int lane = t & 63;
  const int wid = t >> 6;
  const int wr = wid >> 2;   // 0..1 (M)
  const int wc = wid & 3;    // 0..3 (N)
  const int lr = lane & 15;
  const int kg = lane >> 4;  // 0..3

  const int m0 = blockIdx.x * 64;
  const int b = m0 >> 12;
  const int s0 = m0 & (S_LEN - 1);

  // A staging: chunk t -> row=t>>3 (0..63), phys slot=t&7, logical slot = phys ^ (row&7)
  const int arow = t >> 3;
  const int aps = t & 7;
  const int als = aps ^ (arow & 7);
  const unsigned short* asrc_base =
      (als < 4 ? xph : xpl) + ((size_t)b * (S_LEN + 2) + (s0 + arow)) * C_DIM + (als & 3) * 8;

  // B staging: 8 chunks c = r*512+t -> row=c>>3 (0..511)
  const unsigned short* bsrc_base[8];
#pragma unroll
  for (int r = 0; r < 8; ++r) {
    int c = r * 512 + t;
    int row = c >> 3;
    int ls = (c & 7) ^ (row & 7);
    bsrc_base[r] = (ls < 4 ? wh : wl) + (size_t)row * C_DIM + (ls & 3) * 8;
  }

  facc acc[2][8];
#pragma unroll
  for (int fm = 0; fm < 2; ++fm)
#pragma unroll
    for (int fn = 0; fn < 8; ++fn) acc[fm][fn] = (facc)0.f;

  for (int q = 0; q < 48; ++q) {
    const int dk = q >> 4;
    const int ci0 = (q & 15) << 5;
    __syncthreads();
    // stage A (dk*C_DIM shifts one padded row; ci0 shifts cols)
    gload16(asrc_base + dk * C_DIM + ci0, &At[t * 8]);
    // stage B
    const size_t boff = (size_t)dk * (C_DIM * C_DIM) + ci0;
#pragma unroll
    for (int r = 0; r < 8; ++r) gload16(bsrc_base[r] + boff, &Bt[(r * 512 + t) * 8]);
    __syncthreads();

    bfrag ah[2], al[2];
#pragma unroll
    for (int fm = 0; fm < 2; ++fm) {
      int row = wr * 32 + fm * 16 + lr;
      int ph = kg ^ (row & 7);
      int pl = (4 + kg) ^ (row & 7);
      ah[fm] = *(const bfrag*)&At[row * 64 + ph * 8];
      al[fm] = *(const bfrag*)&At[row * 64 + pl * 8];
    }
#pragma unroll
    for (int fn = 0; fn < 8; ++fn) {
      int col = wc * 128 + fn * 16 + lr;
      int ph = kg ^ (col & 7);
      int pl = (4 + kg) ^ (col & 7);
      bfrag bh = *(const bfrag*)&Bt[col * 64 + ph * 8];
      bfrag bl = *(const bfrag*)&Bt[col * 64 + pl * 8];
#pragma unroll
      for (int fm = 0; fm < 2; ++fm) {
        acc[fm][fn] = __builtin_amdgcn_mfma_f32_16x16x32_bf16(ah[fm], bh, acc[fm][fn], 0, 0, 0);
        acc[fm][fn] = __builtin_amdgcn_mfma_f32_16x16x32_bf16(al[fm], bh, acc[fm][fn], 0, 0, 0);
        acc[fm][fn] = __builtin_amdgcn_mfma_f32_16x16x32_bf16(ah[fm], bl, acc[fm][fn], 0, 0, 0);
      }
    }
  }

  // ---------------- epilogue: bias + LN + GELU + proj + sigmoid (rows = m0..m0+63)
  __syncthreads();
  float* red = (float*)At;          // [64][4]
  float* mrow = (float*)At + 256;   // [64]
  float* srow = (float*)At + 320;   // [64]

  float cb8[8], g8[8], be8[8], w8[8];
#pragma unroll
  for (int fn = 0; fn < 8; ++fn) {
    int col = wc * 128 + fn * 16 + lr;
    cb8[fn] = conv_b[col];
    g8[fn] = ln_g[col];
    be8[fn] = ln_b[col];
    w8[fn] = pw[col];
  }
#pragma unroll
  for (int fm = 0; fm < 2; ++fm)
#pragma unroll
    for (int fn = 0; fn < 8; ++fn)
#pragma unroll
      for (int j = 0; j < 4; ++j) acc[fm][fn][j] += cb8[fn];

  // pass 1: mean
#pragma unroll
  for (int fm = 0; fm < 2; ++fm)
#pragma unroll
    for (int j = 0; j < 4; ++j) {
      float s = 0.f;
#pragma unroll
      for (int fn = 0; fn < 8; ++fn) s += acc[fm][fn][j];
      s += __shfl_xor(s, 1, 64); s += __shfl_xor(s, 2, 64);
      s += __shfl_xor(s, 4, 64); s += __shfl_xor(s, 8, 64);
      if (lr == 0) red[(wr * 32 + fm * 16 + kg * 4 + j) * 4 + wc] = s;
    }
  __syncthreads();
  if (t < 64) mrow[t] = (red[t * 4] + red[t * 4 + 1] + red[t * 4 + 2] + red[t * 4 + 3]) * (1.f / 512.f);
  __syncthreads();
  float mu[2][4];
#pragma unroll
  for (int fm = 0; fm < 2; ++fm)
#pragma unroll
    for (int j = 0; j < 4; ++j) mu[fm][j] = mrow[wr * 32 + fm * 16 + kg * 4 + j];

  // pass 2: var
#pragma unroll
  for (int fm = 0; fm < 2; ++fm)
#pragma unroll
    for (int j = 0; j < 4; ++j) {
      float s = 0.f;
#pragma unroll
      for (int fn = 0; fn < 8; ++fn) {
        float d = acc[fm][fn][j] - mu[fm][j];
        s += d * d;
      }
      s += __shfl_xor(s, 1, 64); s += __shfl_xor(s, 2, 64);
      s += __shfl_xor(s, 4, 64); s += __shfl_xor(s, 8, 64);
      if (lr == 0) red[(wr * 32 + fm * 16 + kg * 4 + j) * 4 + wc] = s;
    }
  __syncthreads();
  if (t < 64) srow[t] = 1.0f / sqrtf((red[t * 4] + red[t * 4 + 1] + red[t * 4 + 2] + red[t * 4 + 3]) * (1.f / 512.f) + 1e-5f);
  __syncthreads();
  float rs[2][4];
#pragma unroll
  for (int fm = 0; fm < 2; ++fm)
#pragma unroll
    for (int j = 0; j < 4; ++j) rs[fm][j] = srow[wr * 32 + fm * 16 + kg * 4 + j];

  // pass 3: gelu + proj dot
#pragma unroll
  for (int fm = 0; fm < 2; ++fm)
#pragma unroll
    for (int j = 0; j < 4; ++j) {
      float s = 0.f;
#pragma unroll
      for (int fn = 0; fn < 8; ++fn) {
        float y = (acc[fm][fn][j] - mu[fm][j]) * rs[fm][j] * g8[fn] + be8[fn];
        float gel = 0.5f * y * (1.0f + erff(y * 0.70710678118654752440f));
        s += gel * w8[fn];
      }
      s += __shfl_xor(s, 1, 64); s += __shfl_xor(s, 2, 64);
      s += __shfl_xor(s, 4, 64); s += __shfl_xor(s, 8, 64);
      if (lr == 0) red[(wr * 32 + fm * 16 + kg * 4 + j) * 4 + wc] = s;
    }
  __syncthreads();
  if (t < 64) {
    float z = red[t * 4] + red[t * 4 + 1] + red[t * 4 + 2] + red[t * 4 + 3] + pb[0];
    float a = 1.f / (1.f + expf(-z));
    int pos = m0 + t;
    if (mask[pos]) a = 0.f;
    alpha[pos] = a;
  }
}

// ------------------------------------------------ per-batch alpha sum
__global__ __launch_bounds__(256) void k_asum(const float* __restrict__ alpha, float* __restrict__ asum) {
  __shared__ float red[256];
  const int b = blockIdx.x;
  const int t = threadIdx.x;
  float s = 0.f;
  for (int i = t; i < S_LEN; i += 256) s += alpha[(size_t)b * S_LEN + i];
  red[t] = s;
  __syncthreads();
  for (int k = 128; k > 0; k >>= 1) {
    if (t < k) red[t] += red[t + k];
    __syncthreads();
  }
  if (t == 0) asum[b] = red[0];
}

// ------------------------------------------------ sequential scan (matches np.cumsum order)
__global__ __launch_bounds__(256) void k_scan(const float* __restrict__ alpha,
                                              const float* __restrict__ asum,
                                              const int* __restrict__ tlen,
                                              float* __restrict__ alphaS,
                                              float* __restrict__ csum,
                                              int* __restrict__ ridx) {
  __shared__ float buf[B_DIM][257];
  __shared__ float cbuf[B_DIM][257];
  __shared__ int ibuf[B_DIM][257];
  __shared__ float run[B_DIM];
  __shared__ float scl[B_DIM];
  const int t = threadIdx.x;
  if (t < B_DIM) {
    run[t] = 0.f;
    float desired = 1.0f * (float)tlen[t] + 1e-4f;
    scl[t] = desired / asum[t];
  }
  __syncthreads();
  for (int c = 0; c < 16; ++c) {
#pragma unroll
    for (int r = 0; r < B_DIM; ++r)
      buf[r][t] = alpha[(size_t)r * S_LEN + c * 256 + t];
    __syncthreads();
    if (t < B_DIM) {
      float r = run[t];
      const float sc = scl[t];
      for (int ss = 0; ss < 256; ++ss) {
        float a = buf[t][ss] * sc;
        r += a;
        buf[t][ss] = a;
        cbuf[t][ss] = r;
        int ri = (int)floorf(r);
        ibuf[t][ss] = ri > TMAXI ? TMAXI : ri;
      }
      run[t] = r;
    }
    __syncthreads();
#pragma unroll
    for (int r = 0; r < B_DIM; ++r) {
      size_t g = (size_t)r * S_LEN + c * 256 + t;
      alphaS[g] = buf[r][t];
      csum[g] = cbuf[r][t];
      ridx[g] = ibuf[r][t];
    }
    __syncthreads();
  }
}

// ------------------------------------------------ gather output rows
__device__ __forceinline__ int lower_bound(const int* __restrict__ R, int v) {
  int lo = 0, hi = S_LEN;
  while (lo < hi) {
    int m = (lo + hi) >> 1;
    if (R[m] < v) lo = m + 1; else hi = m;
  }
  return lo;
}

__global__ __launch_bounds__(128) void k_out(const float* __restrict__ x,
                                             const float* __restrict__ alphaS,
                                             const float* __restrict__ csum,
                                             const int* __restrict__ ridx,
                                             const int* __restrict__ tlen,
                                             float* __restrict__ out) {
  const int b = blockIdx.y;
  const int tt = blockIdx.x;
  const int c4 = threadIdx.x;
  float4 acc = {0.f, 0.f, 0.f, 0.f};

  if (tt < tlen[b]) {
    const int* R = ridx + (size_t)b * S_LEN;
    const float* aS = alphaS + (size_t)b * S_LEN;
    const float* cS = csum + (size_t)b * S_LEN;
    int lo = lower_bound(R, tt);
    int hi = lower_bound(R, tt + 1);
    if (hi > S_LEN - 1) hi = S_LEN - 1;
    const float* xb = x + ((size_t)b * S_LEN) * C_DIM + c4 * 4;
    for (int s = lo; s <= hi; ++s) {
      int Rs = R[s];
      int Ls = (s > 0) ? R[s - 1] : 0;
      int fire = Rs - Ls;
      float a = aS[s];
      float cs = cS[s];
      float rw = (fire > 0) ? (cs - (float)Rs) : 0.f;
      int extra = (fire > 1) ? (fire - 1) : 0;
      float lw = a - rw - (float)extra;
      float wgt = 0.f;
      if (Ls == tt) wgt += lw;
      if (fire > 0 && Rs == tt) wgt += rw;
      int t1 = (Ls + 1 < TMAXI) ? (Ls + 1) : TMAXI;
      int t2 = (t1 + 1 < TMAXI) ? (t1 + 1) : TMAXI;
      if (extra >= 1 && t1 == tt) wgt += 1.0f;
      if (extra >= 2 && t2 == tt) wgt += 1.0f;
      if (wgt != 0.f) {
        const float4 xv = *(const float4*)&xb[(size_t)s * C_DIM];
        acc.x = fmaf(wgt, xv.x, acc.x);
        acc.y = fmaf(wgt, xv.y, acc.y);
        acc.z = fmaf(wgt, xv.z, acc.z);
        acc.w = fmaf(wgt, xv.w, acc.w);
      }
    }
  }
  *(float4*)&out[(((size_t)b * TMAXI) + tt) * C_DIM + c4 * 4] = acc;
}

// ---------------------------------------------------------------- launch
extern "C" void kernel_launch(void* const* d_in, const int* in_sizes, int n_in,
                              void* d_out, int out_size, void* d_ws, size_t ws_size,
                              hipStream_t stream) {
  const float* x = (const float*)d_in[0];
  const unsigned char* mask = (const unsigned char*)d_in[1];
  const int* tlen = (const int*)d_in[2];
  const float* conv_w = (const float*)d_in[3];
  const float* conv_b = (const float*)d_in[4];
  const float* ln_g = (const float*)d_in[5];
  const float* ln_b = (const float*)d_in[6];
  const float* proj_w = (const float*)d_in[7];
  const float* proj_b = (const float*)d_in[8];
  float* out = (float*)d_out;

  char* ws = (char*)d_ws;
  const size_t n_pos = (size_t)B_DIM * S_LEN;                    // 65536
  const size_t xp_elems = (size_t)B_DIM * (S_LEN + 2) * C_DIM;   // 33,570,816

  unsigned short* xph = (unsigned short*)ws;
  unsigned short* xpl = xph + xp_elems;
  unsigned short* wh = xpl + xp_elems;
  unsigned short* wl = wh + (size_t)3 * C_DIM * C_DIM;
  char* p = (char*)(wl + (size_t)3 * C_DIM * C_DIM);
  float* alpha = (float*)p;   p += n_pos * 4;
  float* alphaS = (float*)p;  p += n_pos * 4;
  float* csumb = (float*)p;   p += n_pos * 4;
  int* ridx = (int*)p;        p += n_pos * 4;
  float* asum = (float*)p;

  k_split_w<<<(C_DIM * C_DIM + 255) / 256, 256, 0, stream>>>(conv_w, wh, wl);
  k_split_x<<<(int)((xp_elems / 8 + 255) / 256), 256, 0, stream>>>(x, xph, xpl);
  k_fused<<<(B_DIM * S_LEN) / 64, 512, 0, stream>>>(xph, xpl, wh, wl, conv_b, ln_g, ln_b,
                                                    proj_w, proj_b, mask, alpha);
  k_asum<<<B_DIM, 256, 0, stream>>>(alpha, asum);
  k_scan<<<1, 256, 0, stream>>>(alpha, asum, tlen, alphaS, csumb, ridx);
  k_out<<<dim3(TMAXI, B_DIM), 128, 0, stream>>>(x, alphaS, csumb, ridx, tlen, out);
}